// Round 8
// baseline (251.681 us; speedup 1.0000x reference)
//
#include <hip/hip_runtime.h>
#include <hip/hip_bf16.h>

#define NN   50000
#define NE   800000
#define F_IN 128
#define F_H  128
#define F_O  64

#define BINSHIFT 7                       // 128 nodes per bin
#define NBINS    ((NN + 127) >> 7)       // 391
#define CAP      2816                    // mean 2048, sd ~45 -> +17 sigma
#define EPB      8192                    // edges per binning block (two-pass)
#define NBW      12500                   // node-blocks per slice in agg (NN/4)

static constexpr int NB_G1  = (NN + 255) / 256;        // 196 GEMM1 blocks (256 rows each)
static constexpr int NB_BIN = (NE + EPB - 1) / EPB;    // 98 binning blocks

typedef __bf16 bf16_8 __attribute__((ext_vector_type(8)));
typedef float  f32x4  __attribute__((ext_vector_type(4)));

// ---------------------------------------------------------------------------
// MFMA GEMM body, 256 rows/block (W staged ONCE, then 4 x 64-row groups —
// r7's 64-row blocks re-staged W 782x; staging was ~2/3 of the role's work).
// W swizzled to B-fragment layout [ks][c][q][r][j] (r-stride 16B: all 8 LDS
// bank-groups covered). Output optionally SLICED: Y[s][node][32] with
// slice s = col>>5, so 3.2MB feature-slices fit an XCD's 4MB L2 for gathers.
// mfma_f32_16x16x32_bf16: A[m=lane&15][k=(lane>>4)*8+j],
//                         B[k][n=lane&15], D[row=(lane>>4)*4+reg][col=lane&15].
// ---------------------------------------------------------------------------
template <typename AT, int K, int NOUT, bool SCALE, bool SLICED>
__device__ __forceinline__ void gemm_body256(const AT* __restrict__ X,
                                             const float* __restrict__ W,
                                             const float* __restrict__ dinv,
                                             __hip_bfloat16* __restrict__ Y,
                                             __hip_bfloat16* WB, int blk) {
    constexpr int NKS = K / 32;
    constexpr int NC  = NOUT / 16;
    const int t = threadIdx.x;
    for (int f = t; f < K * NOUT; f += 256) {
        int k = f / NOUT, n = f % NOUT;
        int ks = k >> 5, kr = k & 31, qq = kr >> 3, jj = kr & 7;
        int c = n >> 4, nn = n & 15;
        WB[(((ks * NC + c) * 4 + qq) * 16 + nn) * 8 + jj] = __float2bfloat16(W[f]);
    }
    __syncthreads();

    const int wave = t >> 6, lane = t & 63;
    const int r = lane & 15, q = lane >> 4;

    for (int g = 0; g < 4; ++g) {
        const int m0 = blk * 256 + g * 64 + wave * 16;
        int arow = m0 + r;
        if (arow >= NN) arow = NN - 1;  // clamp: garbage rows computed, never stored

        f32x4 acc[NC];
#pragma unroll
        for (int c = 0; c < NC; ++c) acc[c] = (f32x4){0.f, 0.f, 0.f, 0.f};

#pragma unroll
        for (int ks = 0; ks < NKS; ++ks) {
            bf16_8 a;
            if constexpr (sizeof(AT) == 4) {
                const float* xp = (const float*)X + (size_t)arow * K + ks * 32 + q * 8;
                float4 x0 = ((const float4*)xp)[0];
                float4 x1 = ((const float4*)xp)[1];
                a[0] = (__bf16)x0.x; a[1] = (__bf16)x0.y; a[2] = (__bf16)x0.z; a[3] = (__bf16)x0.w;
                a[4] = (__bf16)x1.x; a[5] = (__bf16)x1.y; a[6] = (__bf16)x1.z; a[7] = (__bf16)x1.w;
            } else {
                a = *(const bf16_8*)((const __hip_bfloat16*)X + (size_t)arow * K + ks * 32 + q * 8);
            }
#pragma unroll
            for (int c = 0; c < NC; ++c) {
                bf16_8 b = *(const bf16_8*)&WB[(((ks * NC + c) * 4 + q) * 16 + r) * 8];
                acc[c] = __builtin_amdgcn_mfma_f32_16x16x32_bf16(a, b, acc[c], 0, 0, 0);
            }
        }

#pragma unroll
        for (int c = 0; c < NC; ++c) {
#pragma unroll
            for (int i = 0; i < 4; ++i) {
                int gr = m0 + q * 4 + i;
                if (gr < NN) {
                    float v = acc[c][i];
                    if constexpr (SCALE) v *= dinv[gr];
                    size_t yo;
                    if constexpr (SLICED)
                        yo = (size_t)(c >> 1) * NN * 32 + (size_t)gr * 32 + (c & 1) * 16 + r;
                    else
                        yo = (size_t)gr * NOUT + c * 16 + r;
                    Y[yo] = __float2bfloat16(v);
                }
            }
        }
    }
}

// ---------------------------------------------------------------------------
// Fused: blocks [0, NB_BIN): bin edges by dst>>7 into packed binbuf, two-pass
//        (hist -> chunk reservation -> scatter); EPB=8192 keeps per-(block,bin)
//        chunks >= a cache line (no partial-line write amplification).
//        blocks [NB_BIN, ...): GEMM1 (x@W1 -> Xw SLICED, unscaled).
// Packed entry: (src << 7) | (dst & 127).  bincnt[b] ends as bin total.
// ---------------------------------------------------------------------------
__global__ __launch_bounds__(256) void k_fuseA(const float* __restrict__ X,
                                               const float* __restrict__ W1,
                                               __hip_bfloat16* __restrict__ Xw,
                                               const int* __restrict__ ei32,
                                               int* __restrict__ binbuf,
                                               unsigned* __restrict__ bincnt) {
    __shared__ __align__(16) char smem[32768];  // GEMM WB (32KB) / binning hists
    const int t = threadIdx.x;

    if (blockIdx.x >= NB_BIN) {
        gemm_body256<float, F_IN, F_H, false, true>(X, W1, nullptr, Xw,
                                                    (__hip_bfloat16*)smem,
                                                    blockIdx.x - NB_BIN);
        return;
    }

    // ---- binning role (two-pass) ----
    unsigned* hist = (unsigned*)smem;        // [NBINS]
    unsigned* base = hist + NBINS;           // [NBINS]
    unsigned* rank = base + NBINS;           // [NBINS]
    for (int i = t; i < NBINS; i += 256) { hist[i] = 0u; rank[i] = 0u; }
    __syncthreads();

    const bool is64 = ((ei32[1] | ei32[3] | ei32[5] | ei32[7]) == 0);
    const long long* p64 = (const long long*)ei32;
    const int e0 = blockIdx.x * EPB;
    const int e1 = (e0 + EPB < NE) ? e0 + EPB : NE;

    for (int e = e0 + t; e < e1; e += 256) {
        int d = is64 ? (int)p64[NE + e] : ei32[NE + e];
        atomicAdd(&hist[d >> BINSHIFT], 1u);
    }
    __syncthreads();
    for (int b = t; b < NBINS; b += 256)
        base[b] = atomicAdd(&bincnt[b], hist[b]);  // reserve contiguous chunk
    __syncthreads();
    for (int e = e0 + t; e < e1; e += 256) {
        int s, d;
        if (is64) { s = (int)p64[e]; d = (int)p64[NE + e]; }
        else      { s = ei32[e];     d = ei32[NE + e]; }
        int b = d >> BINSHIFT;
        unsigned rk = atomicAdd(&rank[b], 1u);
        binbuf[(size_t)b * CAP + base[b] + rk] = (s << BINSHIFT) | (d & 127);
    }
}

// ---------------------------------------------------------------------------
// Phase B (one block per bin): inlined global scan of bincnt, local 128-node
// histogram + LDS scan -> row_ptr/dinv/cursors, scatter src ids into CSR,
// then PRESCALE this bin's Xw rows by dinv[node] (removes the per-edge
// dinv[src] random gathers from agg1: sum_e dinv[s]Xw[s] = sum_e Xw'[s],
// self term dinv[v]Xw[v] = Xw'[v]).
// ---------------------------------------------------------------------------
__global__ __launch_bounds__(256) void k_phaseB(const int* __restrict__ binbuf,
                                                const unsigned* __restrict__ bincnt,
                                                unsigned* __restrict__ row_ptr,
                                                float* __restrict__ dinv,
                                                int* __restrict__ srcs,
                                                __hip_bfloat16* __restrict__ Xw) {
    __shared__ unsigned h[128];
    __shared__ unsigned cur[128];
    __shared__ float    dv[128];
    __shared__ unsigned red[256];
    const int b = blockIdx.x, t = threadIdx.x;

    // base = sum_{i<b} bincnt[i]
    unsigned part = 0;
    for (int i = t; i < NBINS; i += 256)
        if (i < b) part += bincnt[i];
    red[t] = part;
    if (t < 128) h[t] = 0u;
    __syncthreads();
    for (int off = 128; off > 0; off >>= 1) {
        if (t < off) red[t] += red[t + off];
        __syncthreads();
    }
    const unsigned gbase = red[0];

    const unsigned n = bincnt[b];
    const int* buf = binbuf + (size_t)b * CAP;
    for (unsigned i = t; i < n; i += 256)
        atomicAdd(&h[buf[i] & 127], 1u);
    __syncthreads();
    if (t < 128) cur[t] = h[t];
    __syncthreads();
    for (int off = 1; off < 128; off <<= 1) {
        unsigned u = (t < 128 && t >= off) ? cur[t - off] : 0u;
        __syncthreads();
        if (t < 128) cur[t] += u;
        __syncthreads();
    }
    if (t < 128) {
        unsigned ex = gbase + cur[t] - h[t];  // global exclusive prefix
        int node = (b << BINSHIFT) + t;
        float d = rsqrtf((float)(h[t] + 1u));  // +1 self-loop
        dv[t] = d;
        if (node < NN) {
            row_ptr[node] = ex;
            dinv[node]    = d;
        }
        cur[t] = ex;  // cursor
    }
    if (b == NBINS - 1 && t == 0) row_ptr[NN] = NE;
    __syncthreads();
    for (unsigned i = t; i < n; i += 256) {
        int p = buf[i];
        unsigned pos = atomicAdd(&cur[p & 127], 1u);
        srcs[pos] = p >> BINSHIFT;
    }

    // prescale this bin's Xw rows (sliced layout [s][node][32])
    for (int idx = t; idx < 128 * 16; idx += 256) {
        int nl = idx >> 4, ch = idx & 15;
        int node = (b << BINSHIFT) + nl;
        if (node < NN) {
            int sl = ch >> 2, cc = ch & 3;
            __hip_bfloat16* p = Xw + (size_t)sl * NN * 32 + (size_t)node * 32 + cc * 8;
            bf16_8 v = *(const bf16_8*)p;
            float d = dv[nl];
            bf16_8 o;
#pragma unroll
            for (int j = 0; j < 8; ++j) o[j] = (__bf16)(d * (float)v[j]);
            *(bf16_8*)p = o;
        }
    }
}

// ---------------------------------------------------------------------------
// Layer-1 aggregation, feature-sliced: grid = 4 slices x 12500 node-blocks
// (slice-major order -> each XCD's L2 holds the 3.2MB slice it gathers from).
// One wave per (node, slice): 4 lanes x 16B cover the 64B sliced row,
// 16 edge-slots (sub), 2 rows in flight, 4-step shfl reduce.
// Xw is prescaled: H = relu(dinv[v]*(sum_e Xw'[s] + Xw'[v]) + b1)
// ---------------------------------------------------------------------------
__global__ __launch_bounds__(256) void k_agg1(const __hip_bfloat16* __restrict__ Xw,
                                              const int* __restrict__ srcs,
                                              const unsigned* __restrict__ row_ptr,
                                              const float* __restrict__ dinv,
                                              const float* __restrict__ b1,
                                              __hip_bfloat16* __restrict__ H) {
    const int wave = threadIdx.x >> 6, lane = threadIdx.x & 63;
    const int sl = blockIdx.x / NBW;
    const int wv = (blockIdx.x % NBW) * 4 + wave;
    if (wv >= NN) return;
    const int fl = lane & 3, sub = lane >> 2;
    const __hip_bfloat16* Xs = Xw + (size_t)sl * NN * 32;

    float acc0[8], acc1[8];
    {   // self term (prescaled): counted once via sub 0
        bf16_8 r = *(const bf16_8*)(Xs + (size_t)wv * 32 + fl * 8);
#pragma unroll
        for (int j = 0; j < 8; ++j) {
            acc0[j] = (sub == 0) ? (float)r[j] : 0.f;
            acc1[j] = 0.f;
        }
    }
    const unsigned i1 = row_ptr[wv + 1];
    unsigned i = row_ptr[wv] + sub;
    for (; i + 16 < i1; i += 32) {
        int s0 = srcs[i], s1 = srcs[i + 16];
        bf16_8 r0 = *(const bf16_8*)(Xs + (size_t)s0 * 32 + fl * 8);
        bf16_8 r1 = *(const bf16_8*)(Xs + (size_t)s1 * 32 + fl * 8);
#pragma unroll
        for (int j = 0; j < 8; ++j) {
            acc0[j] += (float)r0[j];
            acc1[j] += (float)r1[j];
        }
    }
    if (i < i1) {
        bf16_8 r = *(const bf16_8*)(Xs + (size_t)srcs[i] * 32 + fl * 8);
#pragma unroll
        for (int j = 0; j < 8; ++j) acc0[j] += (float)r[j];
    }
#pragma unroll
    for (int j = 0; j < 8; ++j) {
        float a = acc0[j] + acc1[j];
        a += __shfl_xor(a, 4, 64);
        a += __shfl_xor(a, 8, 64);
        a += __shfl_xor(a, 16, 64);
        a += __shfl_xor(a, 32, 64);
        acc0[j] = a;
    }
    if (sub == 0) {
        float dn = dinv[wv];
        bf16_8 o;
#pragma unroll
        for (int j = 0; j < 8; ++j)
            o[j] = (__bf16)fmaxf(dn * acc0[j] + b1[sl * 32 + fl * 8 + j], 0.f);
        *(bf16_8*)(H + (size_t)wv * F_H + sl * 32 + fl * 8) = o;
    }
}

// Layer 2 GEMM (Hw = dinv * (H1 @ W2), SLICED output), 256 rows/block.
__global__ __launch_bounds__(256) void k_gemm2(const __hip_bfloat16* __restrict__ H1,
                                               const float* __restrict__ W2,
                                               const float* __restrict__ dinv,
                                               __hip_bfloat16* __restrict__ Hw) {
    __shared__ __align__(16) __hip_bfloat16 WB[F_H * F_O];
    gemm_body256<__hip_bfloat16, F_H, F_O, true, true>(H1, W2, dinv, Hw, WB, blockIdx.x);
}

// ---------------------------------------------------------------------------
// Layer-2 aggregation, feature-sliced: grid = 2 slices x 12500 node-blocks.
// Hw prescaled by dinv[src].  out = dinv[v]*(sum_e Hw[s] + Hw[v]) + b2  (f32)
// ---------------------------------------------------------------------------
__global__ __launch_bounds__(256) void k_agg2(const __hip_bfloat16* __restrict__ Hw,
                                              const int* __restrict__ srcs,
                                              const unsigned* __restrict__ row_ptr,
                                              const float* __restrict__ dinv,
                                              const float* __restrict__ b2,
                                              float* __restrict__ out) {
    const int wave = threadIdx.x >> 6, lane = threadIdx.x & 63;
    const int sl = blockIdx.x / NBW;
    const int wv = (blockIdx.x % NBW) * 4 + wave;
    if (wv >= NN) return;
    const int fl = lane & 3, sub = lane >> 2;
    const __hip_bfloat16* Hs = Hw + (size_t)sl * NN * 32;

    float acc0[8], acc1[8];
    {
        bf16_8 r = *(const bf16_8*)(Hs + (size_t)wv * 32 + fl * 8);
#pragma unroll
        for (int j = 0; j < 8; ++j) {
            acc0[j] = (sub == 0) ? (float)r[j] : 0.f;
            acc1[j] = 0.f;
        }
    }
    const unsigned i1 = row_ptr[wv + 1];
    unsigned i = row_ptr[wv] + sub;
    for (; i + 16 < i1; i += 32) {
        int s0 = srcs[i], s1 = srcs[i + 16];
        bf16_8 r0 = *(const bf16_8*)(Hs + (size_t)s0 * 32 + fl * 8);
        bf16_8 r1 = *(const bf16_8*)(Hs + (size_t)s1 * 32 + fl * 8);
#pragma unroll
        for (int j = 0; j < 8; ++j) {
            acc0[j] += (float)r0[j];
            acc1[j] += (float)r1[j];
        }
    }
    if (i < i1) {
        bf16_8 r = *(const bf16_8*)(Hs + (size_t)srcs[i] * 32 + fl * 8);
#pragma unroll
        for (int j = 0; j < 8; ++j) acc0[j] += (float)r[j];
    }
#pragma unroll
    for (int j = 0; j < 8; ++j) {
        float a = acc0[j] + acc1[j];
        a += __shfl_xor(a, 4, 64);
        a += __shfl_xor(a, 8, 64);
        a += __shfl_xor(a, 16, 64);
        a += __shfl_xor(a, 32, 64);
        acc0[j] = a;
    }
    if (sub == 0) {
        float dn = dinv[wv];
        float4 o0 = make_float4(dn * acc0[0] + b2[sl * 32 + fl * 8 + 0],
                                dn * acc0[1] + b2[sl * 32 + fl * 8 + 1],
                                dn * acc0[2] + b2[sl * 32 + fl * 8 + 2],
                                dn * acc0[3] + b2[sl * 32 + fl * 8 + 3]);
        float4 o1 = make_float4(dn * acc0[4] + b2[sl * 32 + fl * 8 + 4],
                                dn * acc0[5] + b2[sl * 32 + fl * 8 + 5],
                                dn * acc0[6] + b2[sl * 32 + fl * 8 + 6],
                                dn * acc0[7] + b2[sl * 32 + fl * 8 + 7]);
        float4* op = (float4*)(out + (size_t)wv * F_O + sl * 32 + fl * 8);
        op[0] = o0;
        op[1] = o1;
    }
}

// ---------------------------------------------------------------------------
extern "C" void kernel_launch(void* const* d_in, const int* in_sizes, int n_in,
                              void* d_out, int out_size, void* d_ws, size_t ws_size,
                              hipStream_t stream) {
    const float* x  = (const float*)d_in[0];
    const int*   ei = (const int*)d_in[1];
    const float* W1 = (const float*)d_in[2];
    const float* b1 = (const float*)d_in[3];
    const float* W2 = (const float*)d_in[4];
    const float* b2 = (const float*)d_in[5];
    float* out = (float*)d_out;

    char* w = (char*)d_ws;
    size_t off = 0;
    auto alloc = [&](size_t bytes) {
        void* p = w + off;
        off += (bytes + 255) & ~(size_t)255;
        return p;
    };
    unsigned* row_ptr = (unsigned*)alloc((size_t)(NN + 1) * 4);
    float*    dinv    = (float*)alloc((size_t)NN * 4);
    unsigned* bincnt  = (unsigned*)alloc((size_t)NBINS * 4);
    int*      srcs    = (int*)alloc((size_t)NE * 4);
    int*      binbuf  = (int*)alloc((size_t)NBINS * CAP * 4);
    __hip_bfloat16* Xw = (__hip_bfloat16*)alloc((size_t)NN * F_H * 2);  // reused as Hw
    __hip_bfloat16* H1 = (__hip_bfloat16*)alloc((size_t)NN * F_H * 2);
    __hip_bfloat16* Hw = Xw;  // alias: Xw dead after k_agg1

    hipMemsetAsync(bincnt, 0, (size_t)NBINS * 4, stream);
    k_fuseA<<<NB_BIN + NB_G1, 256, 0, stream>>>(x, W1, Xw, ei, binbuf, bincnt);
    k_phaseB<<<NBINS, 256, 0, stream>>>(binbuf, bincnt, row_ptr, dinv, srcs, Xw);

    k_agg1<<<4 * NBW, 256, 0, stream>>>(Xw, srcs, row_ptr, dinv, b1, H1);
    k_gemm2<<<NB_G1, 256, 0, stream>>>(H1, W2, dinv, Hw);
    k_agg2<<<2 * NBW, 256, 0, stream>>>(Hw, srcs, row_ptr, dinv, b2, out);
}

// Round 9
// 192.546 us; speedup vs baseline: 1.3071x; 1.3071x over previous
//
#include <hip/hip_runtime.h>
#include <hip/hip_bf16.h>

#define NN   50000
#define NE   800000
#define F_IN 128
#define F_H  128
#define F_O  64

#define BINSHIFT 7                       // 128 nodes per bin
#define NBINS    ((NN + 127) >> 7)       // 391
#define CAP      2816                    // mean 2048, sd ~45 -> +17 sigma
#define EPB      8192                    // edges per binning block (two-pass)

static constexpr int NB_G1  = (NN + 255) / 256;        // 196 GEMM blocks (256 rows)
static constexpr int NB_BIN = (NE + EPB - 1) / EPB;    // 98 binning blocks

typedef __bf16 bf16_8 __attribute__((ext_vector_type(8)));
typedef float  f32x4  __attribute__((ext_vector_type(4)));

// ---------------------------------------------------------------------------
// MFMA GEMM body, 256 rows/block (W staged ONCE per block — 64-row blocks
// re-staged W 782x and staging dominated). W swizzled to B-fragment layout
// [ks][c][q][r][j] (r-stride 16B: all 8 LDS bank-groups covered; the r6
// [..][r][q] layout caused 4x LDS serialization). A-loads for all K-steps
// hoisted upfront (8 loads in flight) — fuseA runs at low occupancy, so
// per-wave MLP is the latency lever.
// mfma_f32_16x16x32_bf16: A[m=lane&15][k=(lane>>4)*8+j],
//                         B[k][n=lane&15], D[row=(lane>>4)*4+reg][col=lane&15].
// ---------------------------------------------------------------------------
template <typename AT, int K, int NOUT, bool SCALE>
__device__ __forceinline__ void gemm_body256(const AT* __restrict__ X,
                                             const float* __restrict__ W,
                                             const float* __restrict__ dinv,
                                             __hip_bfloat16* __restrict__ Y,
                                             __hip_bfloat16* WB, int blk) {
    constexpr int NKS = K / 32;
    constexpr int NC  = NOUT / 16;
    const int t = threadIdx.x;
    for (int f = t; f < K * NOUT; f += 256) {
        int k = f / NOUT, n = f % NOUT;
        int ks = k >> 5, kr = k & 31, qq = kr >> 3, jj = kr & 7;
        int c = n >> 4, nn = n & 15;
        WB[(((ks * NC + c) * 4 + qq) * 16 + nn) * 8 + jj] = __float2bfloat16(W[f]);
    }
    __syncthreads();

    const int wave = t >> 6, lane = t & 63;
    const int r = lane & 15, q = lane >> 4;

    for (int g = 0; g < 4; ++g) {
        const int m0 = blk * 256 + g * 64 + wave * 16;
        int arow = m0 + r;
        if (arow >= NN) arow = NN - 1;  // clamp: garbage rows computed, never stored

        // hoist all A-fragment loads for this row (8 or 4 loads in flight)
        bf16_8 afrag[NKS];
        if constexpr (sizeof(AT) == 4) {
            float4 xa[NKS * 2];
            const float4* xp = (const float4*)((const float*)X + (size_t)arow * K);
#pragma unroll
            for (int ks = 0; ks < NKS; ++ks) {
                xa[ks * 2]     = xp[ks * 8 + q * 2];
                xa[ks * 2 + 1] = xp[ks * 8 + q * 2 + 1];
            }
#pragma unroll
            for (int ks = 0; ks < NKS; ++ks) {
                float4 x0 = xa[ks * 2], x1 = xa[ks * 2 + 1];
                afrag[ks][0] = (__bf16)x0.x; afrag[ks][1] = (__bf16)x0.y;
                afrag[ks][2] = (__bf16)x0.z; afrag[ks][3] = (__bf16)x0.w;
                afrag[ks][4] = (__bf16)x1.x; afrag[ks][5] = (__bf16)x1.y;
                afrag[ks][6] = (__bf16)x1.z; afrag[ks][7] = (__bf16)x1.w;
            }
        } else {
            const __hip_bfloat16* xp = (const __hip_bfloat16*)X + (size_t)arow * K;
#pragma unroll
            for (int ks = 0; ks < NKS; ++ks)
                afrag[ks] = *(const bf16_8*)(xp + ks * 32 + q * 8);
        }

        f32x4 acc[NC];
#pragma unroll
        for (int c = 0; c < NC; ++c) acc[c] = (f32x4){0.f, 0.f, 0.f, 0.f};
#pragma unroll
        for (int ks = 0; ks < NKS; ++ks) {
#pragma unroll
            for (int c = 0; c < NC; ++c) {
                bf16_8 b = *(const bf16_8*)&WB[(((ks * NC + c) * 4 + q) * 16 + r) * 8];
                acc[c] = __builtin_amdgcn_mfma_f32_16x16x32_bf16(afrag[ks], b, acc[c], 0, 0, 0);
            }
        }

#pragma unroll
        for (int c = 0; c < NC; ++c) {
#pragma unroll
            for (int i = 0; i < 4; ++i) {
                int gr = m0 + q * 4 + i;
                if (gr < NN) {
                    float v = acc[c][i];
                    if constexpr (SCALE) v *= dinv[gr];
                    Y[(size_t)gr * NOUT + c * 16 + r] = __float2bfloat16(v);
                }
            }
        }
    }
}

// ---------------------------------------------------------------------------
// Fused: blocks [0, NB_BIN): bin edges by dst>>7 into packed binbuf, two-pass
//        (hist -> chunk reservation -> scatter); EPB=8192 keeps per-(block,bin)
//        chunks >= a cache line (no partial-line write amplification).
//        blocks [NB_BIN, ...): GEMM1 (x@W1 -> Xw, raw; prescaled later by
//        phaseB, so zero dependency on the CSR chain).
// Packed entry: (src << 7) | (dst & 127).  bincnt[b] ends as bin total.
// ---------------------------------------------------------------------------
__global__ __launch_bounds__(256) void k_fuseA(const float* __restrict__ X,
                                               const float* __restrict__ W1,
                                               __hip_bfloat16* __restrict__ Xw,
                                               const int* __restrict__ ei32,
                                               int* __restrict__ binbuf,
                                               unsigned* __restrict__ bincnt) {
    __shared__ __align__(16) char smem[32768];  // GEMM WB (32KB) / binning hists
    const int t = threadIdx.x;

    if (blockIdx.x >= NB_BIN) {
        gemm_body256<float, F_IN, F_H, false>(X, W1, nullptr, Xw,
                                              (__hip_bfloat16*)smem,
                                              blockIdx.x - NB_BIN);
        return;
    }

    // ---- binning role (two-pass) ----
    unsigned* hist = (unsigned*)smem;        // [NBINS]
    unsigned* base = hist + NBINS;           // [NBINS]
    unsigned* rank = base + NBINS;           // [NBINS]
    for (int i = t; i < NBINS; i += 256) { hist[i] = 0u; rank[i] = 0u; }
    __syncthreads();

    const bool is64 = ((ei32[1] | ei32[3] | ei32[5] | ei32[7]) == 0);
    const long long* p64 = (const long long*)ei32;
    const int e0 = blockIdx.x * EPB;
    const int e1 = (e0 + EPB < NE) ? e0 + EPB : NE;

    for (int e = e0 + t; e < e1; e += 256) {
        int d = is64 ? (int)p64[NE + e] : ei32[NE + e];
        atomicAdd(&hist[d >> BINSHIFT], 1u);
    }
    __syncthreads();
    for (int b = t; b < NBINS; b += 256)
        base[b] = atomicAdd(&bincnt[b], hist[b]);  // reserve contiguous chunk
    __syncthreads();
    for (int e = e0 + t; e < e1; e += 256) {
        int s, d;
        if (is64) { s = (int)p64[e]; d = (int)p64[NE + e]; }
        else      { s = ei32[e];     d = ei32[NE + e]; }
        int b = d >> BINSHIFT;
        unsigned rk = atomicAdd(&rank[b], 1u);
        binbuf[(size_t)b * CAP + base[b] + rk] = (s << BINSHIFT) | (d & 127);
    }
}

// ---------------------------------------------------------------------------
// Phase B (one block per bin): inlined global scan of bincnt, local 128-node
// histogram + LDS scan -> row_ptr/dinv/cursors, scatter src ids into CSR,
// then PRESCALE this bin's 128 Xw rows by dinv (32KB, L2-hot). Prescaling
// removes 800k random 4B dinv[src] gathers + 1.6M mults from agg1:
// sum_e dinv[s]Xw[s] = sum_e Xw'[s], self term dinv[v]Xw[v] = Xw'[v].
// ---------------------------------------------------------------------------
__global__ __launch_bounds__(256) void k_phaseB(const int* __restrict__ binbuf,
                                                const unsigned* __restrict__ bincnt,
                                                unsigned* __restrict__ row_ptr,
                                                float* __restrict__ dinv,
                                                int* __restrict__ srcs,
                                                __hip_bfloat16* __restrict__ Xw) {
    __shared__ unsigned h[128];
    __shared__ unsigned cur[128];
    __shared__ float    dv[128];
    __shared__ unsigned red[256];
    const int b = blockIdx.x, t = threadIdx.x;

    // base = sum_{i<b} bincnt[i]
    unsigned part = 0;
    for (int i = t; i < NBINS; i += 256)
        if (i < b) part += bincnt[i];
    red[t] = part;
    if (t < 128) h[t] = 0u;
    __syncthreads();
    for (int off = 128; off > 0; off >>= 1) {
        if (t < off) red[t] += red[t + off];
        __syncthreads();
    }
    const unsigned gbase = red[0];

    const unsigned n = bincnt[b];
    const int* buf = binbuf + (size_t)b * CAP;
    for (unsigned i = t; i < n; i += 256)
        atomicAdd(&h[buf[i] & 127], 1u);
    __syncthreads();
    if (t < 128) cur[t] = h[t];
    __syncthreads();
    for (int off = 1; off < 128; off <<= 1) {
        unsigned u = (t < 128 && t >= off) ? cur[t - off] : 0u;
        __syncthreads();
        if (t < 128) cur[t] += u;
        __syncthreads();
    }
    if (t < 128) {
        unsigned ex = gbase + cur[t] - h[t];  // global exclusive prefix
        int node = (b << BINSHIFT) + t;
        float d = rsqrtf((float)(h[t] + 1u));  // +1 self-loop
        dv[t] = d;
        if (node < NN) {
            row_ptr[node] = ex;
            dinv[node]    = d;
        }
        cur[t] = ex;  // cursor
    }
    if (b == NBINS - 1 && t == 0) row_ptr[NN] = NE;
    __syncthreads();
    for (unsigned i = t; i < n; i += 256) {
        int p = buf[i];
        unsigned pos = atomicAdd(&cur[p & 127], 1u);
        srcs[pos] = p >> BINSHIFT;
    }

    // prescale this bin's Xw rows by dinv (row-major, 256B rows)
    for (int idx = t; idx < 128 * 16; idx += 256) {
        int nl = idx >> 4, ch = idx & 15;
        int node = (b << BINSHIFT) + nl;
        if (node < NN) {
            __hip_bfloat16* p = Xw + (size_t)node * F_H + ch * 8;
            bf16_8 v = *(const bf16_8*)p;
            float d = dv[nl];
            bf16_8 o;
#pragma unroll
            for (int j = 0; j < 8; ++j) o[j] = (__bf16)(d * (float)v[j]);
            *(bf16_8*)p = o;
        }
    }
}

// ---------------------------------------------------------------------------
// Layer-1 aggregation: one wave per node, 16 lanes x 16B per gathered row,
// 4 edge slots, 2 rows in flight per slot. Xw is PRESCALED:
// H = relu(dinv[v]*(sum_e Xw'[s] + Xw'[v]) + b1)
// ---------------------------------------------------------------------------
__global__ __launch_bounds__(256) void k_agg1(const __hip_bfloat16* __restrict__ Xw,
                                              const int* __restrict__ srcs,
                                              const unsigned* __restrict__ row_ptr,
                                              const float* __restrict__ dinv,
                                              const float* __restrict__ b1,
                                              __hip_bfloat16* __restrict__ H) {
    const int wv   = (blockIdx.x * 256 + threadIdx.x) >> 6;
    const int lane = threadIdx.x & 63;
    if (wv >= NN) return;
    const int sub = lane >> 4;      // 0..3
    const int fl  = lane & 15;      // feature slice: 8*fl .. 8*fl+7

    float acc0[8], acc1[8];
    bf16_8 self = *(const bf16_8*)(Xw + (size_t)wv * F_H + fl * 8);
#pragma unroll
    for (int j = 0; j < 8; ++j) {
        acc0[j] = (sub == 0) ? (float)self[j] : 0.f;
        acc1[j] = 0.f;
    }

    const unsigned ie = row_ptr[wv + 1];
    unsigned i = row_ptr[wv] + sub;
    for (; i + 4 < ie; i += 8) {   // two groups of 4 edges in flight
        int s0 = srcs[i], s1 = srcs[i + 4];
        bf16_8 r0 = *(const bf16_8*)(Xw + (size_t)s0 * F_H + fl * 8);
        bf16_8 r1 = *(const bf16_8*)(Xw + (size_t)s1 * F_H + fl * 8);
#pragma unroll
        for (int j = 0; j < 8; ++j) {
            acc0[j] += (float)r0[j];
            acc1[j] += (float)r1[j];
        }
    }
    if (i < ie) {
        bf16_8 r = *(const bf16_8*)(Xw + (size_t)srcs[i] * F_H + fl * 8);
#pragma unroll
        for (int j = 0; j < 8; ++j) acc0[j] += (float)r[j];
    }
#pragma unroll
    for (int j = 0; j < 8; ++j) {
        float a = acc0[j] + acc1[j];
        a += __shfl_xor(a, 16, 64);
        a += __shfl_xor(a, 32, 64);
        acc0[j] = a;
    }
    if (sub == 0) {
        float dn = dinv[wv];
        bf16_8 o;
#pragma unroll
        for (int j = 0; j < 8; ++j) {
            float v = fmaxf(dn * acc0[j] + b1[fl * 8 + j], 0.f);
            o[j] = (__bf16)v;
        }
        *(bf16_8*)(H + (size_t)wv * F_H + fl * 8) = o;
    }
}

// Layer 2 GEMM (Hw = dinv * (H1 @ W2)), 256 rows/block.
__global__ __launch_bounds__(256) void k_gemm2(const __hip_bfloat16* __restrict__ H1,
                                               const float* __restrict__ W2,
                                               const float* __restrict__ dinv,
                                               __hip_bfloat16* __restrict__ Hw) {
    __shared__ __align__(16) __hip_bfloat16 WB[F_H * F_O];
    gemm_body256<__hip_bfloat16, F_H, F_O, true>(H1, W2, dinv, Hw, WB, blockIdx.x);
}

// ---------------------------------------------------------------------------
// Layer-2 aggregation: one wave per node, 8 lanes x 16B per row, 2 row-gathers
// in flight per slot (16 edges per wave-iteration). Hw pre-scaled by dinv[src].
// out = dinv[v]*(sum_e Hw[s] + Hw[v]) + b2   (f32 output)
// ---------------------------------------------------------------------------
__global__ __launch_bounds__(256) void k_agg2(const __hip_bfloat16* __restrict__ Hw,
                                              const int* __restrict__ srcs,
                                              const unsigned* __restrict__ row_ptr,
                                              const float* __restrict__ dinv,
                                              const float* __restrict__ b2,
                                              float* __restrict__ out) {
    const int wv   = (blockIdx.x * 256 + threadIdx.x) >> 6;
    const int lane = threadIdx.x & 63;
    if (wv >= NN) return;
    const int sub = lane >> 3;      // 0..7
    const int fl  = lane & 7;       // feature slice: 8*fl .. 8*fl+7

    float acc0[8], acc1[8];
    bf16_8 self = *(const bf16_8*)(Hw + (size_t)wv * F_O + fl * 8);
#pragma unroll
    for (int j = 0; j < 8; ++j) {
        acc0[j] = (sub == 0) ? (float)self[j] : 0.f;
        acc1[j] = 0.f;
    }

    const unsigned ie = row_ptr[wv + 1];
    unsigned i = row_ptr[wv] + sub;
    for (; i + 8 < ie; i += 16) {  // two groups of 8 edges in flight
        int s0 = srcs[i], s1 = srcs[i + 8];
        bf16_8 r0 = *(const bf16_8*)(Hw + (size_t)s0 * F_O + fl * 8);
        bf16_8 r1 = *(const bf16_8*)(Hw + (size_t)s1 * F_O + fl * 8);
#pragma unroll
        for (int j = 0; j < 8; ++j) {
            acc0[j] += (float)r0[j];
            acc1[j] += (float)r1[j];
        }
    }
    if (i < ie) {
        bf16_8 r = *(const bf16_8*)(Hw + (size_t)srcs[i] * F_O + fl * 8);
#pragma unroll
        for (int j = 0; j < 8; ++j) acc0[j] += (float)r[j];
    }
#pragma unroll
    for (int j = 0; j < 8; ++j) {
        float a = acc0[j] + acc1[j];
        a += __shfl_xor(a, 8, 64);
        a += __shfl_xor(a, 16, 64);
        a += __shfl_xor(a, 32, 64);
        acc0[j] = a;
    }
    if (sub == 0) {
        float dn = dinv[wv];
        float4 o0 = make_float4(dn * acc0[0] + b2[fl * 8 + 0], dn * acc0[1] + b2[fl * 8 + 1],
                                dn * acc0[2] + b2[fl * 8 + 2], dn * acc0[3] + b2[fl * 8 + 3]);
        float4 o1 = make_float4(dn * acc0[4] + b2[fl * 8 + 4], dn * acc0[5] + b2[fl * 8 + 5],
                                dn * acc0[6] + b2[fl * 8 + 6], dn * acc0[7] + b2[fl * 8 + 7]);
        float4* op = (float4*)(out + (size_t)wv * F_O + fl * 8);
        op[0] = o0;
        op[1] = o1;
    }
}

// ---------------------------------------------------------------------------
extern "C" void kernel_launch(void* const* d_in, const int* in_sizes, int n_in,
                              void* d_out, int out_size, void* d_ws, size_t ws_size,
                              hipStream_t stream) {
    const float* x  = (const float*)d_in[0];
    const int*   ei = (const int*)d_in[1];
    const float* W1 = (const float*)d_in[2];
    const float* b1 = (const float*)d_in[3];
    const float* W2 = (const float*)d_in[4];
    const float* b2 = (const float*)d_in[5];
    float* out = (float*)d_out;

    char* w = (char*)d_ws;
    size_t off = 0;
    auto alloc = [&](size_t bytes) {
        void* p = w + off;
        off += (bytes + 255) & ~(size_t)255;
        return p;
    };
    unsigned* row_ptr = (unsigned*)alloc((size_t)(NN + 1) * 4);
    float*    dinv    = (float*)alloc((size_t)NN * 4);
    unsigned* bincnt  = (unsigned*)alloc((size_t)NBINS * 4);
    int*      srcs    = (int*)alloc((size_t)NE * 4);
    int*      binbuf  = (int*)alloc((size_t)NBINS * CAP * 4);
    __hip_bfloat16* Xw = (__hip_bfloat16*)alloc((size_t)NN * F_H * 2);  // reused as Hw
    __hip_bfloat16* H1 = (__hip_bfloat16*)alloc((size_t)NN * F_H * 2);
    __hip_bfloat16* Hw = Xw;  // alias: Xw dead after k_agg1

    hipMemsetAsync(bincnt, 0, (size_t)NBINS * 4, stream);
    k_fuseA<<<NB_BIN + NB_G1, 256, 0, stream>>>(x, W1, Xw, ei, binbuf, bincnt);
    k_phaseB<<<NBINS, 256, 0, stream>>>(binbuf, bincnt, row_ptr, dinv, srcs, Xw);

    k_agg1<<<(NN + 3) / 4, 256, 0, stream>>>(Xw, srcs, row_ptr, dinv, b1, H1);
    k_gemm2<<<NB_G1, 256, 0, stream>>>(H1, W2, dinv, Hw);
    k_agg2<<<(NN + 3) / 4, 256, 0, stream>>>(Hw, srcs, row_ptr, dinv, b2, out);
}

// Round 10
// 191.419 us; speedup vs baseline: 1.3148x; 1.0059x over previous
//
#include <hip/hip_runtime.h>
#include <hip/hip_bf16.h>

#define NN   50000
#define NE   800000
#define F_IN 128
#define F_H  128
#define F_O  64

#define BINSHIFT 7                       // 128 nodes per bin
#define NBINS    ((NN + 127) >> 7)       // 391
#define CAP      2816                    // mean 2048, sd ~45 -> +17 sigma
#define EPB      8192                    // edges per binning block (two-pass)
#define NCHUNK   782                     // 64-node chunks ((NN+63)/64)

static constexpr int NB_G1  = (NN + 255) / 256;        // 196 GEMM blocks (256 rows)
static constexpr int NB_BIN = (NE + EPB - 1) / EPB;    // 98 binning blocks

typedef __bf16 bf16_8 __attribute__((ext_vector_type(8)));
typedef float  f32x4  __attribute__((ext_vector_type(4)));

// ---------------------------------------------------------------------------
// MFMA GEMM body, 256 rows/block, W staged ONCE per block, swizzled to
// B-fragment layout [ks][c][q][r][j] (r-stride 16B: all 8 LDS bank-groups).
// No A-hoist (r9's hoist: VGPR 44->100, occupancy halved, 0 time gain).
// Output SLICED: Y[sl][node][32], sl = feature>>5 — 3.2MB slices so agg
// gathers can live in one XCD's 4MB L2.
// mfma_f32_16x16x32_bf16: A[m=lane&15][k=(lane>>4)*8+j],
//                         B[k][n=lane&15], D[row=(lane>>4)*4+reg][col=lane&15].
// ---------------------------------------------------------------------------
template <typename AT, int K, int NOUT, bool SCALE>
__device__ __forceinline__ void gemm_body256(const AT* __restrict__ X,
                                             const float* __restrict__ W,
                                             const float* __restrict__ dinv,
                                             __hip_bfloat16* __restrict__ Y,
                                             __hip_bfloat16* WB, int blk) {
    constexpr int NKS = K / 32;
    constexpr int NC  = NOUT / 16;
    const int t = threadIdx.x;
    for (int f = t; f < K * NOUT; f += 256) {
        int k = f / NOUT, n = f % NOUT;
        int ks = k >> 5, kr = k & 31, qq = kr >> 3, jj = kr & 7;
        int c = n >> 4, nn = n & 15;
        WB[(((ks * NC + c) * 4 + qq) * 16 + nn) * 8 + jj] = __float2bfloat16(W[f]);
    }
    __syncthreads();

    const int wave = t >> 6, lane = t & 63;
    const int r = lane & 15, q = lane >> 4;

    for (int g = 0; g < 4; ++g) {
        const int m0 = blk * 256 + g * 64 + wave * 16;
        int arow = m0 + r;
        if (arow >= NN) arow = NN - 1;  // clamp: garbage rows computed, never stored

        f32x4 acc[NC];
#pragma unroll
        for (int c = 0; c < NC; ++c) acc[c] = (f32x4){0.f, 0.f, 0.f, 0.f};

#pragma unroll
        for (int ks = 0; ks < NKS; ++ks) {
            bf16_8 a;
            if constexpr (sizeof(AT) == 4) {
                const float* xp = (const float*)X + (size_t)arow * K + ks * 32 + q * 8;
                float4 x0 = ((const float4*)xp)[0];
                float4 x1 = ((const float4*)xp)[1];
                a[0] = (__bf16)x0.x; a[1] = (__bf16)x0.y; a[2] = (__bf16)x0.z; a[3] = (__bf16)x0.w;
                a[4] = (__bf16)x1.x; a[5] = (__bf16)x1.y; a[6] = (__bf16)x1.z; a[7] = (__bf16)x1.w;
            } else {
                a = *(const bf16_8*)((const __hip_bfloat16*)X + (size_t)arow * K + ks * 32 + q * 8);
            }
#pragma unroll
            for (int c = 0; c < NC; ++c) {
                bf16_8 b = *(const bf16_8*)&WB[(((ks * NC + c) * 4 + q) * 16 + r) * 8];
                acc[c] = __builtin_amdgcn_mfma_f32_16x16x32_bf16(a, b, acc[c], 0, 0, 0);
            }
        }

#pragma unroll
        for (int c = 0; c < NC; ++c) {
#pragma unroll
            for (int i = 0; i < 4; ++i) {
                int gr = m0 + q * 4 + i;
                if (gr < NN) {
                    float v = acc[c][i];
                    if constexpr (SCALE) v *= dinv[gr];
                    // sliced: slice = c>>1, within-slice col = (c&1)*16 + r
                    Y[(size_t)(c >> 1) * (NN * 32) + (size_t)gr * 32 + (c & 1) * 16 + r] =
                        __float2bfloat16(v);
                }
            }
        }
    }
}

// ---------------------------------------------------------------------------
// Fused: blocks [0, NB_BIN): bin edges by dst>>7 into packed binbuf, two-pass
//        (hist -> chunk reservation -> scatter); EPB=8192 keeps per-(block,bin)
//        chunks >= a cache line. blocks [NB_BIN, ...): GEMM1 -> Xw sliced, raw
//        (prescaled later by phaseB, so zero dependency on the CSR chain).
// Packed entry: (src << 7) | (dst & 127).  bincnt[b] ends as bin total.
// ---------------------------------------------------------------------------
__global__ __launch_bounds__(256) void k_fuseA(const float* __restrict__ X,
                                               const float* __restrict__ W1,
                                               __hip_bfloat16* __restrict__ Xw,
                                               const int* __restrict__ ei32,
                                               int* __restrict__ binbuf,
                                               unsigned* __restrict__ bincnt) {
    __shared__ __align__(16) char smem[32768];  // GEMM WB (32KB) / binning hists
    const int t = threadIdx.x;

    if (blockIdx.x >= NB_BIN) {
        gemm_body256<float, F_IN, F_H, false>(X, W1, nullptr, Xw,
                                              (__hip_bfloat16*)smem,
                                              blockIdx.x - NB_BIN);
        return;
    }

    // ---- binning role (two-pass) ----
    unsigned* hist = (unsigned*)smem;        // [NBINS]
    unsigned* base = hist + NBINS;           // [NBINS]
    unsigned* rank = base + NBINS;           // [NBINS]
    for (int i = t; i < NBINS; i += 256) { hist[i] = 0u; rank[i] = 0u; }
    __syncthreads();

    const bool is64 = ((ei32[1] | ei32[3] | ei32[5] | ei32[7]) == 0);
    const long long* p64 = (const long long*)ei32;
    const int e0 = blockIdx.x * EPB;
    const int e1 = (e0 + EPB < NE) ? e0 + EPB : NE;

    for (int e = e0 + t; e < e1; e += 256) {
        int d = is64 ? (int)p64[NE + e] : ei32[NE + e];
        atomicAdd(&hist[d >> BINSHIFT], 1u);
    }
    __syncthreads();
    for (int b = t; b < NBINS; b += 256)
        base[b] = atomicAdd(&bincnt[b], hist[b]);  // reserve contiguous chunk
    __syncthreads();
    for (int e = e0 + t; e < e1; e += 256) {
        int s, d;
        if (is64) { s = (int)p64[e]; d = (int)p64[NE + e]; }
        else      { s = ei32[e];     d = ei32[NE + e]; }
        int b = d >> BINSHIFT;
        unsigned rk = atomicAdd(&rank[b], 1u);
        binbuf[(size_t)b * CAP + base[b] + rk] = (s << BINSHIFT) | (d & 127);
    }
}

// ---------------------------------------------------------------------------
// Phase B (one block per bin): inlined global scan of bincnt, local 128-node
// histogram + LDS scan -> row_ptr/dinv/cursors, scatter src ids into CSR,
// then PRESCALE this bin's 128 Xw rows by dinv (sliced layout, L2-hot).
// Prescale removes per-edge dinv[src] gathers from agg1 — essential now that
// sliced agg touches each edge 4x.
// ---------------------------------------------------------------------------
__global__ __launch_bounds__(256) void k_phaseB(const int* __restrict__ binbuf,
                                                const unsigned* __restrict__ bincnt,
                                                unsigned* __restrict__ row_ptr,
                                                float* __restrict__ dinv,
                                                int* __restrict__ srcs,
                                                __hip_bfloat16* __restrict__ Xw) {
    __shared__ unsigned h[128];
    __shared__ unsigned cur[128];
    __shared__ float    dv[128];
    __shared__ unsigned red[256];
    const int b = blockIdx.x, t = threadIdx.x;

    // base = sum_{i<b} bincnt[i]
    unsigned part = 0;
    for (int i = t; i < NBINS; i += 256)
        if (i < b) part += bincnt[i];
    red[t] = part;
    if (t < 128) h[t] = 0u;
    __syncthreads();
    for (int off = 128; off > 0; off >>= 1) {
        if (t < off) red[t] += red[t + off];
        __syncthreads();
    }
    const unsigned gbase = red[0];

    const unsigned n = bincnt[b];
    const int* buf = binbuf + (size_t)b * CAP;
    for (unsigned i = t; i < n; i += 256)
        atomicAdd(&h[buf[i] & 127], 1u);
    __syncthreads();
    if (t < 128) cur[t] = h[t];
    __syncthreads();
    for (int off = 1; off < 128; off <<= 1) {
        unsigned u = (t < 128 && t >= off) ? cur[t - off] : 0u;
        __syncthreads();
        if (t < 128) cur[t] += u;
        __syncthreads();
    }
    if (t < 128) {
        unsigned ex = gbase + cur[t] - h[t];  // global exclusive prefix
        int node = (b << BINSHIFT) + t;
        float d = rsqrtf((float)(h[t] + 1u));  // +1 self-loop
        dv[t] = d;
        if (node < NN) {
            row_ptr[node] = ex;
            dinv[node]    = d;
        }
        cur[t] = ex;  // cursor
    }
    if (b == NBINS - 1 && t == 0) row_ptr[NN] = NE;
    __syncthreads();
    for (unsigned i = t; i < n; i += 256) {
        int p = buf[i];
        unsigned pos = atomicAdd(&cur[p & 127], 1u);
        srcs[pos] = p >> BINSHIFT;
    }

    // prescale this bin's Xw rows (sliced layout [sl][node][32])
    for (int idx = t; idx < 128 * 16; idx += 256) {
        int nl = idx >> 4, ch = idx & 15;
        int node = (b << BINSHIFT) + nl;
        if (node < NN) {
            int sl = ch >> 2, cc = ch & 3;
            __hip_bfloat16* p = Xw + (size_t)sl * (NN * 32) + (size_t)node * 32 + cc * 8;
            bf16_8 v = *(const bf16_8*)p;
            float d = dv[nl];
            bf16_8 o;
#pragma unroll
            for (int j = 0; j < 8; ++j) o[j] = (__bf16)(d * (float)v[j]);
            *(bf16_8*)p = o;
        }
    }
}

// ---------------------------------------------------------------------------
// Layer-1 aggregation, sliced + XCD-affine. Block b: xcd = b&7 (the %8
// dispatch heuristic); slice = (b>>1)&3 (2 XCDs per 3.2MB slice -> slice
// lives in XCD-local L2); chunk = (b>>3)*2 + (b&1) covers [0,782).
// Team-of-4 org: 4 lanes = one node's 64B sliced row, 16 teams/wave,
// sequential edge walk, 2-deep unroll. NO shuffles, no reduction (fixes
// r8's per-wave overhead that sank slicing).
// H = relu(dinv[v]*(sum_e Xw'[s] + Xw'[v]) + b1), H row-major [node][128].
// ---------------------------------------------------------------------------
__global__ __launch_bounds__(256) void k_agg1(const __hip_bfloat16* __restrict__ Xw,
                                              const int* __restrict__ srcs,
                                              const unsigned* __restrict__ row_ptr,
                                              const float* __restrict__ dinv,
                                              const float* __restrict__ b1,
                                              __hip_bfloat16* __restrict__ H) {
    const int b = blockIdx.x;
    const int sl    = (b >> 1) & 3;
    const int chunk = (b >> 3) * 2 + (b & 1);
    const int wave = threadIdx.x >> 6, lane = threadIdx.x & 63;
    const int team = lane >> 2, fl = lane & 3;
    const int wv = chunk * 64 + wave * 16 + team;
    if (wv >= NN) return;
    const __hip_bfloat16* Xs = Xw + (size_t)sl * (NN * 32);

    float acc0[8], acc1[8];
    bf16_8 self = *(const bf16_8*)(Xs + (size_t)wv * 32 + fl * 8);
#pragma unroll
    for (int j = 0; j < 8; ++j) { acc0[j] = (float)self[j]; acc1[j] = 0.f; }

    const unsigned i1 = row_ptr[wv + 1];
    unsigned i = row_ptr[wv];
    for (; i + 1 < i1; i += 2) {
        int s0 = srcs[i], s1 = srcs[i + 1];
        bf16_8 r0 = *(const bf16_8*)(Xs + (size_t)s0 * 32 + fl * 8);
        bf16_8 r1 = *(const bf16_8*)(Xs + (size_t)s1 * 32 + fl * 8);
#pragma unroll
        for (int j = 0; j < 8; ++j) {
            acc0[j] += (float)r0[j];
            acc1[j] += (float)r1[j];
        }
    }
    if (i < i1) {
        bf16_8 r = *(const bf16_8*)(Xs + (size_t)srcs[i] * 32 + fl * 8);
#pragma unroll
        for (int j = 0; j < 8; ++j) acc0[j] += (float)r[j];
    }

    const float dn = dinv[wv];
    bf16_8 o;
#pragma unroll
    for (int j = 0; j < 8; ++j)
        o[j] = (__bf16)fmaxf(dn * (acc0[j] + acc1[j]) + b1[sl * 32 + fl * 8 + j], 0.f);
    *(bf16_8*)(H + (size_t)wv * F_H + sl * 32 + fl * 8) = o;
}

// Layer 2 GEMM (Hw = dinv * (H1 @ W2), sliced output [2][node][32]).
__global__ __launch_bounds__(256) void k_gemm2(const __hip_bfloat16* __restrict__ H1,
                                               const float* __restrict__ W2,
                                               const float* __restrict__ dinv,
                                               __hip_bfloat16* __restrict__ Hw) {
    __shared__ __align__(16) __hip_bfloat16 WB[F_H * F_O];
    gemm_body256<__hip_bfloat16, F_H, F_O, true>(H1, W2, dinv, Hw, WB, blockIdx.x);
}

// ---------------------------------------------------------------------------
// Layer-2 aggregation, sliced + XCD-affine: slice = (b>>2)&1 (4 XCDs per
// slice), chunk = (b>>3)*4 + (b&3) in [0,784) (783/784 guarded by wv>=NN).
// Team-of-4, Hw prescaled.  out = dinv[v]*(sum_e Hw[s] + Hw[v]) + b2  (f32)
// ---------------------------------------------------------------------------
__global__ __launch_bounds__(256) void k_agg2(const __hip_bfloat16* __restrict__ Hw,
                                              const int* __restrict__ srcs,
                                              const unsigned* __restrict__ row_ptr,
                                              const float* __restrict__ dinv,
                                              const float* __restrict__ b2,
                                              float* __restrict__ out) {
    const int b = blockIdx.x;
    const int sl    = (b >> 2) & 1;
    const int chunk = (b >> 3) * 4 + (b & 3);
    const int wave = threadIdx.x >> 6, lane = threadIdx.x & 63;
    const int team = lane >> 2, fl = lane & 3;
    const int wv = chunk * 64 + wave * 16 + team;
    if (wv >= NN) return;
    const __hip_bfloat16* Hs = Hw + (size_t)sl * (NN * 32);

    float acc0[8], acc1[8];
    bf16_8 self = *(const bf16_8*)(Hs + (size_t)wv * 32 + fl * 8);
#pragma unroll
    for (int j = 0; j < 8; ++j) { acc0[j] = (float)self[j]; acc1[j] = 0.f; }

    const unsigned i1 = row_ptr[wv + 1];
    unsigned i = row_ptr[wv];
    for (; i + 1 < i1; i += 2) {
        int s0 = srcs[i], s1 = srcs[i + 1];
        bf16_8 r0 = *(const bf16_8*)(Hs + (size_t)s0 * 32 + fl * 8);
        bf16_8 r1 = *(const bf16_8*)(Hs + (size_t)s1 * 32 + fl * 8);
#pragma unroll
        for (int j = 0; j < 8; ++j) {
            acc0[j] += (float)r0[j];
            acc1[j] += (float)r1[j];
        }
    }
    if (i < i1) {
        bf16_8 r = *(const bf16_8*)(Hs + (size_t)srcs[i] * 32 + fl * 8);
#pragma unroll
        for (int j = 0; j < 8; ++j) acc0[j] += (float)r[j];
    }

    const float dn = dinv[wv];
    float* op = out + (size_t)wv * F_O + sl * 32 + fl * 8;
    float4 o0 = make_float4(dn * (acc0[0] + acc1[0]) + b2[sl * 32 + fl * 8 + 0],
                            dn * (acc0[1] + acc1[1]) + b2[sl * 32 + fl * 8 + 1],
                            dn * (acc0[2] + acc1[2]) + b2[sl * 32 + fl * 8 + 2],
                            dn * (acc0[3] + acc1[3]) + b2[sl * 32 + fl * 8 + 3]);
    float4 o1 = make_float4(dn * (acc0[4] + acc1[4]) + b2[sl * 32 + fl * 8 + 4],
                            dn * (acc0[5] + acc1[5]) + b2[sl * 32 + fl * 8 + 5],
                            dn * (acc0[6] + acc1[6]) + b2[sl * 32 + fl * 8 + 6],
                            dn * (acc0[7] + acc1[7]) + b2[sl * 32 + fl * 8 + 7]);
    ((float4*)op)[0] = o0;
    ((float4*)op)[1] = o1;
}

// ---------------------------------------------------------------------------
extern "C" void kernel_launch(void* const* d_in, const int* in_sizes, int n_in,
                              void* d_out, int out_size, void* d_ws, size_t ws_size,
                              hipStream_t stream) {
    const float* x  = (const float*)d_in[0];
    const int*   ei = (const int*)d_in[1];
    const float* W1 = (const float*)d_in[2];
    const float* b1 = (const float*)d_in[3];
    const float* W2 = (const float*)d_in[4];
    const float* b2 = (const float*)d_in[5];
    float* out = (float*)d_out;

    char* w = (char*)d_ws;
    size_t off = 0;
    auto alloc = [&](size_t bytes) {
        void* p = w + off;
        off += (bytes + 255) & ~(size_t)255;
        return p;
    };
    unsigned* row_ptr = (unsigned*)alloc((size_t)(NN + 1) * 4);
    float*    dinv    = (float*)alloc((size_t)NN * 4);
    unsigned* bincnt  = (unsigned*)alloc((size_t)NBINS * 4);
    int*      srcs    = (int*)alloc((size_t)NE * 4);
    int*      binbuf  = (int*)alloc((size_t)NBINS * CAP * 4);
    __hip_bfloat16* Xw = (__hip_bfloat16*)alloc((size_t)NN * F_H * 2);  // sliced [4][NN][32]
    __hip_bfloat16* H1 = (__hip_bfloat16*)alloc((size_t)NN * F_H * 2);  // row-major
    __hip_bfloat16* Hw = Xw;  // alias: Xw dead after k_agg1; sliced [2][NN][32]

    hipMemsetAsync(bincnt, 0, (size_t)NBINS * 4, stream);
    k_fuseA<<<NB_BIN + NB_G1, 256, 0, stream>>>(x, W1, Xw, ei, binbuf, bincnt);
    k_phaseB<<<NBINS, 256, 0, stream>>>(binbuf, bincnt, row_ptr, dinv, srcs, Xw);

    k_agg1<<<391 * 8, 256, 0, stream>>>(Xw, srcs, row_ptr, dinv, b1, H1);
    k_gemm2<<<NB_G1, 256, 0, stream>>>(H1, W2, dinv, Hw);
    k_agg2<<<196 * 8, 256, 0, stream>>>(Hw, srcs, row_ptr, dinv, b2, out);
}

// Round 11
// 178.442 us; speedup vs baseline: 1.4104x; 1.0727x over previous
//
#include <hip/hip_runtime.h>
#include <hip/hip_bf16.h>

#define NN   50000
#define NE   800000
#define F_IN 128
#define F_H  128
#define F_O  64

#define BINSHIFT 7                       // 128 nodes per bin
#define NBINS    ((NN + 127) >> 7)       // 391
#define CAP      2816                    // mean 2048, sd ~45 -> +17 sigma
#define EPB      8192                    // edges per binning block (two-pass)

static constexpr int NB_GEMM = (NN + 127) / 128;       // 391 GEMM blocks (128 rows, 8 waves)
static constexpr int NB_BIN  = (NE + EPB - 1) / EPB;   // 98 binning blocks

typedef __bf16 bf16_8 __attribute__((ext_vector_type(8)));
typedef float  f32x4  __attribute__((ext_vector_type(4)));

// ---------------------------------------------------------------------------
// MFMA GEMM body, 512 threads / 128 rows per block (8 waves x 16 rows, ONE
// row-group per wave). Rationale: fuseA sat at 44us across 4 structural
// variants — common factor was ~4 waves/CU (1.1 blocks/CU @256thr); this
// form gives ~15 waves/CU. W staged once per block, swizzled to B-fragment
// layout [ks][c][q][r][j] (r-stride 16B: all 8 LDS bank-groups covered —
// the [..][r][q] layout cost 4x LDS serialization, r6).
// No A-hoist (r9: VGPR 44->100, occupancy halved, 0 gain).
// mfma_f32_16x16x32_bf16: A[m=lane&15][k=(lane>>4)*8+j],
//                         B[k][n=lane&15], D[row=(lane>>4)*4+reg][col=lane&15].
// ---------------------------------------------------------------------------
template <typename AT, int K, int NOUT, bool SCALE>
__device__ __forceinline__ void gemm_body512(const AT* __restrict__ X,
                                             const float* __restrict__ W,
                                             const float* __restrict__ dinv,
                                             __hip_bfloat16* __restrict__ Y,
                                             __hip_bfloat16* WB, int blk) {
    constexpr int NKS = K / 32;
    constexpr int NC  = NOUT / 16;
    const int t = threadIdx.x;
    for (int f = t; f < K * NOUT; f += 512) {
        int k = f / NOUT, n = f % NOUT;
        int ks = k >> 5, kr = k & 31, qq = kr >> 3, jj = kr & 7;
        int c = n >> 4, nn = n & 15;
        WB[(((ks * NC + c) * 4 + qq) * 16 + nn) * 8 + jj] = __float2bfloat16(W[f]);
    }
    __syncthreads();

    const int wave = t >> 6, lane = t & 63;
    const int r = lane & 15, q = lane >> 4;
    const int m0 = blk * 128 + wave * 16;
    int arow = m0 + r;
    if (arow >= NN) arow = NN - 1;  // clamp: garbage rows computed, never stored

    f32x4 acc[NC];
#pragma unroll
    for (int c = 0; c < NC; ++c) acc[c] = (f32x4){0.f, 0.f, 0.f, 0.f};

#pragma unroll
    for (int ks = 0; ks < NKS; ++ks) {
        bf16_8 a;
        if constexpr (sizeof(AT) == 4) {
            const float* xp = (const float*)X + (size_t)arow * K + ks * 32 + q * 8;
            float4 x0 = ((const float4*)xp)[0];
            float4 x1 = ((const float4*)xp)[1];
            a[0] = (__bf16)x0.x; a[1] = (__bf16)x0.y; a[2] = (__bf16)x0.z; a[3] = (__bf16)x0.w;
            a[4] = (__bf16)x1.x; a[5] = (__bf16)x1.y; a[6] = (__bf16)x1.z; a[7] = (__bf16)x1.w;
        } else {
            a = *(const bf16_8*)((const __hip_bfloat16*)X + (size_t)arow * K + ks * 32 + q * 8);
        }
#pragma unroll
        for (int c = 0; c < NC; ++c) {
            bf16_8 b = *(const bf16_8*)&WB[(((ks * NC + c) * 4 + q) * 16 + r) * 8];
            acc[c] = __builtin_amdgcn_mfma_f32_16x16x32_bf16(a, b, acc[c], 0, 0, 0);
        }
    }

#pragma unroll
    for (int c = 0; c < NC; ++c) {
#pragma unroll
        for (int i = 0; i < 4; ++i) {
            int gr = m0 + q * 4 + i;
            if (gr < NN) {
                float v = acc[c][i];
                if constexpr (SCALE) v *= dinv[gr];
                Y[(size_t)gr * NOUT + c * 16 + r] = __float2bfloat16(v);
            }
        }
    }
}

// ---------------------------------------------------------------------------
// Fused, 512-thread blocks: blocks [0, NB_BIN): bin edges by dst>>7 into
// packed binbuf, two-pass (hist -> chunk reservation -> scatter); EPB=8192
// keeps per-(block,bin) chunks >= a cache line (no partial-line write amp).
// blocks [NB_BIN, ...): GEMM1 (x@W1 -> Xw raw row-major; prescaled later by
// phaseB, so zero dependency on the CSR chain).
// Packed entry: (src << 7) | (dst & 127).  bincnt[b] ends as bin total.
// ---------------------------------------------------------------------------
__global__ __launch_bounds__(512) void k_fuseA(const float* __restrict__ X,
                                               const float* __restrict__ W1,
                                               __hip_bfloat16* __restrict__ Xw,
                                               const int* __restrict__ ei32,
                                               int* __restrict__ binbuf,
                                               unsigned* __restrict__ bincnt) {
    __shared__ __align__(16) char smem[32768];  // GEMM WB (32KB) / binning hists
    const int t = threadIdx.x;

    if (blockIdx.x >= NB_BIN) {
        gemm_body512<float, F_IN, F_H, false>(X, W1, nullptr, Xw,
                                              (__hip_bfloat16*)smem,
                                              blockIdx.x - NB_BIN);
        return;
    }

    // ---- binning role (two-pass, 8 waves) ----
    unsigned* hist = (unsigned*)smem;        // [NBINS]
    unsigned* base = hist + NBINS;           // [NBINS]
    unsigned* rank = base + NBINS;           // [NBINS]
    for (int i = t; i < NBINS; i += 512) { hist[i] = 0u; rank[i] = 0u; }
    __syncthreads();

    const bool is64 = ((ei32[1] | ei32[3] | ei32[5] | ei32[7]) == 0);
    const long long* p64 = (const long long*)ei32;
    const int e0 = blockIdx.x * EPB;
    const int e1 = (e0 + EPB < NE) ? e0 + EPB : NE;

    for (int e = e0 + t; e < e1; e += 512) {
        int d = is64 ? (int)p64[NE + e] : ei32[NE + e];
        atomicAdd(&hist[d >> BINSHIFT], 1u);
    }
    __syncthreads();
    for (int b = t; b < NBINS; b += 512)
        base[b] = atomicAdd(&bincnt[b], hist[b]);  // reserve contiguous chunk
    __syncthreads();
    for (int e = e0 + t; e < e1; e += 512) {
        int s, d;
        if (is64) { s = (int)p64[e]; d = (int)p64[NE + e]; }
        else      { s = ei32[e];     d = ei32[NE + e]; }
        int b = d >> BINSHIFT;
        unsigned rk = atomicAdd(&rank[b], 1u);
        binbuf[(size_t)b * CAP + base[b] + rk] = (s << BINSHIFT) | (d & 127);
    }
}

// ---------------------------------------------------------------------------
// Phase B (one block per bin): inlined global scan of bincnt, local 128-node
// histogram + LDS scan -> row_ptr/dinv/cursors, scatter src ids into CSR,
// then PRESCALE this bin's 128 Xw rows by dinv (row-major, 32KB, L2-hot).
// Prescale removes 800k random 4B dinv[src] gathers + 1.6M mults from agg1.
// ---------------------------------------------------------------------------
__global__ __launch_bounds__(256) void k_phaseB(const int* __restrict__ binbuf,
                                                const unsigned* __restrict__ bincnt,
                                                unsigned* __restrict__ row_ptr,
                                                float* __restrict__ dinv,
                                                int* __restrict__ srcs,
                                                __hip_bfloat16* __restrict__ Xw) {
    __shared__ unsigned h[128];
    __shared__ unsigned cur[128];
    __shared__ float    dv[128];
    __shared__ unsigned red[256];
    const int b = blockIdx.x, t = threadIdx.x;

    // base = sum_{i<b} bincnt[i]
    unsigned part = 0;
    for (int i = t; i < NBINS; i += 256)
        if (i < b) part += bincnt[i];
    red[t] = part;
    if (t < 128) h[t] = 0u;
    __syncthreads();
    for (int off = 128; off > 0; off >>= 1) {
        if (t < off) red[t] += red[t + off];
        __syncthreads();
    }
    const unsigned gbase = red[0];

    const unsigned n = bincnt[b];
    const int* buf = binbuf + (size_t)b * CAP;
    for (unsigned i = t; i < n; i += 256)
        atomicAdd(&h[buf[i] & 127], 1u);
    __syncthreads();
    if (t < 128) cur[t] = h[t];
    __syncthreads();
    for (int off = 1; off < 128; off <<= 1) {
        unsigned u = (t < 128 && t >= off) ? cur[t - off] : 0u;
        __syncthreads();
        if (t < 128) cur[t] += u;
        __syncthreads();
    }
    if (t < 128) {
        unsigned ex = gbase + cur[t] - h[t];  // global exclusive prefix
        int node = (b << BINSHIFT) + t;
        float d = rsqrtf((float)(h[t] + 1u));  // +1 self-loop
        dv[t] = d;
        if (node < NN) {
            row_ptr[node] = ex;
            dinv[node]    = d;
        }
        cur[t] = ex;  // cursor
    }
    if (b == NBINS - 1 && t == 0) row_ptr[NN] = NE;
    __syncthreads();
    for (unsigned i = t; i < n; i += 256) {
        int p = buf[i];
        unsigned pos = atomicAdd(&cur[p & 127], 1u);
        srcs[pos] = p >> BINSHIFT;
    }

    // prescale this bin's Xw rows by dinv (row-major, 256B rows)
    for (int idx = t; idx < 128 * 16; idx += 256) {
        int nl = idx >> 4, ch = idx & 15;
        int node = (b << BINSHIFT) + nl;
        if (node < NN) {
            __hip_bfloat16* p = Xw + (size_t)node * F_H + ch * 8;
            bf16_8 v = *(const bf16_8*)p;
            float d = dv[nl];
            bf16_8 o;
#pragma unroll
            for (int j = 0; j < 8; ++j) o[j] = (__bf16)(d * (float)v[j]);
            *(bf16_8*)p = o;
        }
    }
}

// ---------------------------------------------------------------------------
// Layer-1 aggregation (r7 proven form): one wave per node, 16 lanes x 16B per
// gathered row, 4 edge slots, 2 rows in flight. Xw PRESCALED:
// H = relu(dinv[v]*(sum_e Xw'[s] + Xw'[v]) + b1)
// ---------------------------------------------------------------------------
__global__ __launch_bounds__(256) void k_agg1(const __hip_bfloat16* __restrict__ Xw,
                                              const int* __restrict__ srcs,
                                              const unsigned* __restrict__ row_ptr,
                                              const float* __restrict__ dinv,
                                              const float* __restrict__ b1,
                                              __hip_bfloat16* __restrict__ H) {
    const int wv   = (blockIdx.x * 256 + threadIdx.x) >> 6;
    const int lane = threadIdx.x & 63;
    if (wv >= NN) return;
    const int sub = lane >> 4;      // 0..3
    const int fl  = lane & 15;      // feature slice: 8*fl .. 8*fl+7

    float acc0[8], acc1[8];
    bf16_8 self = *(const bf16_8*)(Xw + (size_t)wv * F_H + fl * 8);
#pragma unroll
    for (int j = 0; j < 8; ++j) {
        acc0[j] = (sub == 0) ? (float)self[j] : 0.f;
        acc1[j] = 0.f;
    }

    const unsigned ie = row_ptr[wv + 1];
    unsigned i = row_ptr[wv] + sub;
    for (; i + 4 < ie; i += 8) {   // two groups of 4 edges in flight
        int s0 = srcs[i], s1 = srcs[i + 4];
        bf16_8 r0 = *(const bf16_8*)(Xw + (size_t)s0 * F_H + fl * 8);
        bf16_8 r1 = *(const bf16_8*)(Xw + (size_t)s1 * F_H + fl * 8);
#pragma unroll
        for (int j = 0; j < 8; ++j) {
            acc0[j] += (float)r0[j];
            acc1[j] += (float)r1[j];
        }
    }
    if (i < ie) {
        bf16_8 r = *(const bf16_8*)(Xw + (size_t)srcs[i] * F_H + fl * 8);
#pragma unroll
        for (int j = 0; j < 8; ++j) acc0[j] += (float)r[j];
    }
#pragma unroll
    for (int j = 0; j < 8; ++j) {
        float a = acc0[j] + acc1[j];
        a += __shfl_xor(a, 16, 64);
        a += __shfl_xor(a, 32, 64);
        acc0[j] = a;
    }
    if (sub == 0) {
        float dn = dinv[wv];
        bf16_8 o;
#pragma unroll
        for (int j = 0; j < 8; ++j) {
            float v = fmaxf(dn * acc0[j] + b1[fl * 8 + j], 0.f);
            o[j] = (__bf16)v;
        }
        *(bf16_8*)(H + (size_t)wv * F_H + fl * 8) = o;
    }
}

// Layer 2 GEMM (Hw = dinv * (H1 @ W2)), 512 threads / 128 rows.
__global__ __launch_bounds__(512) void k_gemm2(const __hip_bfloat16* __restrict__ H1,
                                               const float* __restrict__ W2,
                                               const float* __restrict__ dinv,
                                               __hip_bfloat16* __restrict__ Hw) {
    __shared__ __align__(16) __hip_bfloat16 WB[F_H * F_O];
    gemm_body512<__hip_bfloat16, F_H, F_O, true>(H1, W2, dinv, Hw, WB, blockIdx.x);
}

// ---------------------------------------------------------------------------
// Layer-2 aggregation (r7 form): one wave per node, 8 lanes x 16B per row,
// 2 rows in flight per slot. Hw pre-scaled by dinv[src].
// out = dinv[v]*(sum_e Hw[s] + Hw[v]) + b2   (f32 output)
// ---------------------------------------------------------------------------
__global__ __launch_bounds__(256) void k_agg2(const __hip_bfloat16* __restrict__ Hw,
                                              const int* __restrict__ srcs,
                                              const unsigned* __restrict__ row_ptr,
                                              const float* __restrict__ dinv,
                                              const float* __restrict__ b2,
                                              float* __restrict__ out) {
    const int wv   = (blockIdx.x * 256 + threadIdx.x) >> 6;
    const int lane = threadIdx.x & 63;
    if (wv >= NN) return;
    const int sub = lane >> 3;      // 0..7
    const int fl  = lane & 7;       // feature slice: 8*fl .. 8*fl+7

    float acc0[8], acc1[8];
    bf16_8 self = *(const bf16_8*)(Hw + (size_t)wv * F_O + fl * 8);
#pragma unroll
    for (int j = 0; j < 8; ++j) {
        acc0[j] = (sub == 0) ? (float)self[j] : 0.f;
        acc1[j] = 0.f;
    }

    const unsigned ie = row_ptr[wv + 1];
    unsigned i = row_ptr[wv] + sub;
    for (; i + 8 < ie; i += 16) {  // two groups of 8 edges in flight
        int s0 = srcs[i], s1 = srcs[i + 8];
        bf16_8 r0 = *(const bf16_8*)(Hw + (size_t)s0 * F_O + fl * 8);
        bf16_8 r1 = *(const bf16_8*)(Hw + (size_t)s1 * F_O + fl * 8);
#pragma unroll
        for (int j = 0; j < 8; ++j) {
            acc0[j] += (float)r0[j];
            acc1[j] += (float)r1[j];
        }
    }
    if (i < ie) {
        bf16_8 r = *(const bf16_8*)(Hw + (size_t)srcs[i] * F_O + fl * 8);
#pragma unroll
        for (int j = 0; j < 8; ++j) acc0[j] += (float)r[j];
    }
#pragma unroll
    for (int j = 0; j < 8; ++j) {
        float a = acc0[j] + acc1[j];
        a += __shfl_xor(a, 8, 64);
        a += __shfl_xor(a, 16, 64);
        a += __shfl_xor(a, 32, 64);
        acc0[j] = a;
    }
    if (sub == 0) {
        float dn = dinv[wv];
        float4 o0 = make_float4(dn * acc0[0] + b2[fl * 8 + 0], dn * acc0[1] + b2[fl * 8 + 1],
                                dn * acc0[2] + b2[fl * 8 + 2], dn * acc0[3] + b2[fl * 8 + 3]);
        float4 o1 = make_float4(dn * acc0[4] + b2[fl * 8 + 4], dn * acc0[5] + b2[fl * 8 + 5],
                                dn * acc0[6] + b2[fl * 8 + 6], dn * acc0[7] + b2[fl * 8 + 7]);
        float4* op = (float4*)(out + (size_t)wv * F_O + fl * 8);
        op[0] = o0;
        op[1] = o1;
    }
}

// ---------------------------------------------------------------------------
extern "C" void kernel_launch(void* const* d_in, const int* in_sizes, int n_in,
                              void* d_out, int out_size, void* d_ws, size_t ws_size,
                              hipStream_t stream) {
    const float* x  = (const float*)d_in[0];
    const int*   ei = (const int*)d_in[1];
    const float* W1 = (const float*)d_in[2];
    const float* b1 = (const float*)d_in[3];
    const float* W2 = (const float*)d_in[4];
    const float* b2 = (const float*)d_in[5];
    float* out = (float*)d_out;

    char* w = (char*)d_ws;
    size_t off = 0;
    auto alloc = [&](size_t bytes) {
        void* p = w + off;
        off += (bytes + 255) & ~(size_t)255;
        return p;
    };
    unsigned* row_ptr = (unsigned*)alloc((size_t)(NN + 1) * 4);
    float*    dinv    = (float*)alloc((size_t)NN * 4);
    unsigned* bincnt  = (unsigned*)alloc((size_t)NBINS * 4);
    int*      srcs    = (int*)alloc((size_t)NE * 4);
    int*      binbuf  = (int*)alloc((size_t)NBINS * CAP * 4);
    __hip_bfloat16* Xw = (__hip_bfloat16*)alloc((size_t)NN * F_H * 2);  // reused as Hw
    __hip_bfloat16* H1 = (__hip_bfloat16*)alloc((size_t)NN * F_H * 2);
    __hip_bfloat16* Hw = Xw;  // alias: Xw dead after k_agg1

    hipMemsetAsync(bincnt, 0, (size_t)NBINS * 4, stream);
    k_fuseA<<<NB_BIN + NB_GEMM, 512, 0, stream>>>(x, W1, Xw, ei, binbuf, bincnt);
    k_phaseB<<<NBINS, 256, 0, stream>>>(binbuf, bincnt, row_ptr, dinv, srcs, Xw);

    k_agg1<<<(NN + 3) / 4, 256, 0, stream>>>(Xw, srcs, row_ptr, dinv, b1, H1);
    k_gemm2<<<NB_GEMM, 512, 0, stream>>>(H1, W2, dinv, Hw);
    k_agg2<<<(NN + 3) / 4, 256, 0, stream>>>(Hw, srcs, row_ptr, dinv, b2, out);
}